// Round 7
// baseline (83.337 us; speedup 1.0000x reference)
//
#include <hip/hip_runtime.h>

#define N_W   8192
#define N_E   32
#define N_NUC 8
#define D_H   32
#define NTAB  4096
#define TAB_INVH 256.0f    // table step = 1/256, range [0, 16)
#define TAB_H    (1.0f/256.0f)
#define WPB   4            // walkers per block; wave = 1 walker (lane = electron x k-half)

// ws layout (float units): [0,4096) ee-table | [4096,4112) aux | [4112,4624) aT[32][16]
// | [4624,4656) W3*scale_en | [4656, +512 u32) W2 bf16 B-fragments
#define AUX_OFF 4096
#define AT_OFF  4112
#define W3S_OFF 4624
#define B_OFF   4656
// aux: [0..7] softplus(b_en), [8] softplus(b_ee), [9] 32*scale_en*b3_en

typedef __attribute__((ext_vector_type(8)))  short bf16x8_t;   // 8 bf16 = 4 VGPR
typedef __attribute__((ext_vector_type(16))) float f32x16_t;   // MFMA accumulator

union FragAB { bf16x8_t s; unsigned u[4]; };

__device__ __forceinline__ float fast_rcp(float x) { return __builtin_amdgcn_rcpf(x); }
__device__ __forceinline__ float silu_f(float v)   { return v * fast_rcp(1.0f + __expf(-v)); }
__device__ __forceinline__ unsigned pk_bf16(float lo, float hi) {
    unsigned r;
    asm("v_cvt_pk_bf16_f32 %0, %1, %2" : "=v"(r) : "v"(lo), "v"(hi));
    return r;
}

// ---------------- Pre-kernel: ee table + aux + pair coefs + W2 bf16 fragments ----------------
__global__ void build_tables(const float* __restrict__ W1ee, const float* __restrict__ b1ee,
                             const float* __restrict__ W2ee, const float* __restrict__ b2ee,
                             const float* __restrict__ W3ee, const float* __restrict__ b3ee,
                             const float* __restrict__ scale_ee,
                             const float* __restrict__ b_en, const float* __restrict__ b_ee,
                             const int* __restrict__ mask,
                             const float* __restrict__ W2en, const float* __restrict__ W3en,
                             const float* __restrict__ b3en, const float* __restrict__ scale_en,
                             float* __restrict__ ws)
{
    const int tid = threadIdx.x;
    if (blockIdx.x == 0) {
        float* aux = ws + AUX_OFF;
        if (tid < N_NUC) aux[tid] = __logf(1.0f + __expf(b_en[tid]));
        if (tid == 8)    aux[8]   = __logf(1.0f + __expf(b_ee[0]));
        if (tid == 9)    aux[9]   = 32.0f * scale_en[0] * b3en[0];
        if (tid < D_H)   ws[W3S_OFF + tid] = W3en[tid] * scale_en[0];
        // aT[e][d-1]: pair (e,(e+d)&31) coef 0.25/0.5, d=16 pre-halved (counted twice)
        float* aT = ws + AT_OFF;
#pragma unroll
        for (int q = 0; q < 2; ++q) {
            int idx = tid + q * 256;               // 512 entries
            int e = idx >> 4, dm = idx & 15, d = dm + 1;
            int jn = (e + d) & 31;
            int a = e < jn ? e : jn, b = e < jn ? jn : e;
            float av = mask[a * N_E + b] ? 0.25f : 0.5f;
            if (d == 16) av *= 0.5f;
            aT[e * 16 + dm] = av;
        }
        // W2_en -> bf16 B-fragments: lane l, slot s (m=s>>2, r=s&3):
        //   k = m*16 + (l>>5)*8 + 2r, j = l&31; packed (lo=k, hi=k+1)
        unsigned* wsB = (unsigned*)(ws + B_OFF);
#pragma unroll
        for (int q = 0; q < 2; ++q) {
            int idx = tid + q * 256;               // 512 = 64 lanes x 8 slots
            int lane = idx >> 3, slot = idx & 7;
            int m = slot >> 2, r = slot & 3;
            int k = m * 16 + ((lane >> 5) << 3) + (r << 1);
            int j = lane & 31;
            wsB[lane * 8 + slot] = pk_bf16(W2en[k * D_H + j], W2en[(k + 1) * D_H + j]);
        }
    }
    // ee table: one entry per 32-lane group, lane j = hidden unit
    const int j     = tid & 31;
    const int entry = blockIdx.x * 8 + (tid >> 5);
    const float r   = (float)entry * TAB_H;
    float g = b2ee[j];
#pragma unroll
    for (int k = 0; k < D_H; ++k) g += silu_f(r * W1ee[k] + b1ee[k]) * W2ee[k * D_H + j];
    float o = silu_f(g) * W3ee[j];
#pragma unroll
    for (int m = 16; m; m >>= 1) o += __shfl_xor(o, m, 32);
    if (j == 0) ws[entry] = scale_ee[0] * (o + b3ee[0]);
}

// ---------------- Main kernel: 1 walker per wave ----------------
// Lane l: electron e = l&31, k-half kh = l>>5. Both halves hold electron e's
// coords and full h[32]; each half silu+packs only its own 16 k-values -> A
// fragments built in-lane (no shfl_xor). Work split by kh: e-e d 1-8 / 9-16;
// cusp duplicated with 0.5 weight. 8192 waves -> 8 waves/SIMD (needs VGPR<=64).
__launch_bounds__(256, 8)
__global__ void jastrow_kernel(const float* __restrict__ re, const float* __restrict__ rnuc,
                               const float* __restrict__ charges,
                               const float* __restrict__ W1, const float* __restrict__ b1,
                               const float* __restrict__ b2,
                               const float* __restrict__ ws,
                               float* __restrict__ out)
{
    const int tid = threadIdx.x;
    const int e   = tid & 31;           // electron
    const int kh  = (tid >> 5) & 1;     // k-half / work-split copy
    const int w   = blockIdx.x * WPB + (tid >> 6);
    const float* aux = ws + AUX_OFF;

    const float* cb = re + ((size_t)w * N_E + e) * 3;
    float ex = cb[0], ey = cb[1], ez = cb[2];

    // ---- e-n cusp (duplicated across halves, weighted 0.5) + r^2 ----
    float x[N_NUC];
    float cusp = 0.0f;
#pragma unroll
    for (int n = 0; n < N_NUC; ++n) {
        float dx = ex - rnuc[n * 3 + 0];
        float dy = ey - rnuc[n * 3 + 1];
        float dz = ez - rnuc[n * 3 + 2];
        float r2 = dx * dx + dy * dy + dz * dz;
        x[n] = r2;
        float r = sqrtf(r2);
        cusp -= charges[n] * r * fast_rcp(1.0f + aux[n] * r);
    }
    float acc = 0.5f * cusp;

    // ---- layer 1: 8 -> 32 full h per lane, fp32 packed, W1 via K$ (256 floats) ----
    float2 hh[D_H / 2];
#pragma unroll
    for (int j = 0; j < D_H / 2; ++j) hh[j] = ((const float2*)b1)[j];
#pragma unroll
    for (int k = 0; k < N_NUC; ++k) {
        float xk = x[k];
        const float2* row = (const float2*)(W1 + k * D_H);
#pragma unroll
        for (int j = 0; j < D_H / 2; ++j) {
            float2 wv = row[j];
            hh[j].x = fmaf(xk, wv.x, hh[j].x);
            hh[j].y = fmaf(xk, wv.y, hh[j].y);
        }
    }
    // select this lane's 16 k-values, silu, pack -> A fragments (no cross-lane)
    // MFMA1 covers k 0..15: lane holds k = kh*8 + 2r(+1)  -> hh[kh*4 + r]
    // MFMA2 covers k 16..31: lane holds k = 16+kh*8+2r(+1) -> hh[8 + kh*4 + r]
    FragAB A1, A2;
#pragma unroll
    for (int r = 0; r < 4; ++r) {
        float2 s1 = kh ? hh[4 + r]  : hh[r];
        float2 s2 = kh ? hh[12 + r] : hh[8 + r];
        A1.u[r] = pk_bf16(silu_f(s1.x), silu_f(s1.y));
        A2.u[r] = pk_bf16(silu_f(s2.x), silu_f(s2.y));
    }

    // B fragments (wave-shared W2, pre-packed)
    FragAB B1, B2;
    {
        const unsigned* wsB = (const unsigned*)(ws + B_OFF) + (size_t)(tid & 63) * 8;
        uint4 q0 = *(const uint4*)wsB;
        uint4 q1 = *(const uint4*)(wsB + 4);
        B1.u[0] = q0.x; B1.u[1] = q0.y; B1.u[2] = q0.z; B1.u[3] = q0.w;
        B2.u[0] = q1.x; B2.u[1] = q1.y; B2.u[2] = q1.z; B2.u[3] = q1.w;
    }

    float vb2 = b2[e];                              // C init = bias (col j = lane&31)
    f32x16_t accm;
#pragma unroll
    for (int r = 0; r < 16; ++r) accm[r] = vb2;
    accm = __builtin_amdgcn_mfma_f32_32x32x16_bf16(A1.s, B1.s, accm, 0, 0, 0);
    accm = __builtin_amdgcn_mfma_f32_32x32x16_bf16(A2.s, B2.s, accm, 0, 0, 0);

    // epilogue: lane covers 16 of 32 rows for col e; rows across the lane pair
    // are disjoint -> every (row,col) counted once over the wave
    float w3s = ws[W3S_OFF + e];
    float sA = 0.0f;
#pragma unroll
    for (int r = 0; r < 16; ++r) sA += silu_f(accm[r]);
    acc += sA * w3s;

    // ---- e-e: 8 rotation pairs per half (kh=0: d 1..8, kh=1: d 9..16) ----
    float bs = aux[8];
    float av[8];
    {
        const float* aT = ws + AT_OFF + e * 16 + kh * 8;
#pragma unroll
        for (int i = 0; i < 8; ++i) av[i] = aT[i];
    }
#pragma unroll
    for (int dd = 0; dd < 8; ++dd) {
        int d = kh * 8 + dd + 1;
        int jn = (e + d) & 31;
        float cjx = __shfl(ex, jn, 32);
        float cjy = __shfl(ey, jn, 32);
        float cjz = __shfl(ez, jn, 32);
        float dx = ex - cjx, dy = ey - cjy, dz = ez - cjz;
        float r = sqrtf(dx * dx + dy * dy + dz * dz);
        float ct = av[dd] * r * fast_rcp(1.0f + bs * r);
        float t = r * TAB_INVH;
        int i0 = (int)t;
        if (i0 > NTAB - 2) i0 = NTAB - 2;
        float f = t - (float)i0;
        const float* tp = ws + i0;
        float tv = tp[0] + f * (tp[1] - tp[0]);
        if (dd == 7) tv = kh ? 0.5f * tv : tv;      // d=16 pairs counted twice
        acc += ct + tv;
    }

    // ---- reduce 64 lanes (one walker) ----
#pragma unroll
    for (int m = 32; m; m >>= 1) acc += __shfl_xor(acc, m, 64);
    if ((tid & 63) == 0) out[w] = acc + aux[9];
}

extern "C" void kernel_launch(void* const* d_in, const int* in_sizes, int n_in,
                              void* d_out, int out_size, void* d_ws, size_t ws_size,
                              hipStream_t stream)
{
    const float* re       = (const float*)d_in[0];
    const float* rnuc     = (const float*)d_in[1];
    const float* charges  = (const float*)d_in[2];
    const int*   mask     = (const int*)d_in[3];
    const float* b_en     = (const float*)d_in[4];
    const float* b_ee     = (const float*)d_in[5];
    const float* W1_en    = (const float*)d_in[6];
    const float* b1_en    = (const float*)d_in[7];
    const float* W2_en    = (const float*)d_in[8];
    const float* b2_en    = (const float*)d_in[9];
    const float* W3_en    = (const float*)d_in[10];
    const float* b3_en    = (const float*)d_in[11];
    const float* W1_ee    = (const float*)d_in[12];
    const float* b1_ee    = (const float*)d_in[13];
    const float* W2_ee    = (const float*)d_in[14];
    const float* b2_ee    = (const float*)d_in[15];
    const float* W3_ee    = (const float*)d_in[16];
    const float* b3_ee    = (const float*)d_in[17];
    const float* scale_en = (const float*)d_in[18];
    const float* scale_ee = (const float*)d_in[19];

    float* out = (float*)d_out;
    float* ws  = (float*)d_ws;

    build_tables<<<NTAB / 8, 256, 0, stream>>>(W1_ee, b1_ee, W2_ee, b2_ee, W3_ee, b3_ee,
                                               scale_ee, b_en, b_ee, mask,
                                               W2_en, W3_en, b3_en, scale_en, ws);
    jastrow_kernel<<<N_W / WPB, 256, 0, stream>>>(re, rnuc, charges,
                                                  W1_en, b1_en, b2_en, ws, out);
}

// Round 8
// 41.821 us; speedup vs baseline: 1.9927x; 1.9927x over previous
//
#include <hip/hip_runtime.h>

#define N_W   8192
#define N_E   32
#define N_NUC 8
#define D_H   32
#define NTAB  4096
#define TAB_INVH 256.0f    // table step = 1/256, range [0, 16)
#define TAB_H    (1.0f/256.0f)
#define WPB   4            // walkers per block; wave = 1 walker (lane = electron x k-half)

// ws layout (float units): [0,4096) ee-table | [4096,4112) aux | [4112,4624) aT[32][16]
// | [4624,4656) W3*scale_en | [4656, +512 u32) W2 bf16 B-fragments
#define AUX_OFF 4096
#define AT_OFF  4112
#define W3S_OFF 4624
#define B_OFF   4656
// aux: [0..7] softplus(b_en), [8] softplus(b_ee), [9] 32*scale_en*b3_en

typedef __attribute__((ext_vector_type(8)))  short bf16x8_t;   // 8 bf16 = 4 VGPR
typedef __attribute__((ext_vector_type(16))) float f32x16_t;   // MFMA accumulator

union FragAB { bf16x8_t s; unsigned u[4]; };

__device__ __forceinline__ float fast_rcp(float x) { return __builtin_amdgcn_rcpf(x); }
__device__ __forceinline__ float silu_f(float v)   { return v * fast_rcp(1.0f + __expf(-v)); }
__device__ __forceinline__ unsigned pk_bf16(float lo, float hi) {
    unsigned r;
    asm("v_cvt_pk_bf16_f32 %0, %1, %2" : "=v"(r) : "v"(lo), "v"(hi));
    return r;
}

// ---------------- Pre-kernel: ee table + aux + pair coefs + W2 bf16 fragments ----------------
__global__ void build_tables(const float* __restrict__ W1ee, const float* __restrict__ b1ee,
                             const float* __restrict__ W2ee, const float* __restrict__ b2ee,
                             const float* __restrict__ W3ee, const float* __restrict__ b3ee,
                             const float* __restrict__ scale_ee,
                             const float* __restrict__ b_en, const float* __restrict__ b_ee,
                             const int* __restrict__ mask,
                             const float* __restrict__ W2en, const float* __restrict__ W3en,
                             const float* __restrict__ b3en, const float* __restrict__ scale_en,
                             float* __restrict__ ws)
{
    const int tid = threadIdx.x;
    if (blockIdx.x == 0) {
        float* aux = ws + AUX_OFF;
        if (tid < N_NUC) aux[tid] = __logf(1.0f + __expf(b_en[tid]));
        if (tid == 8)    aux[8]   = __logf(1.0f + __expf(b_ee[0]));
        if (tid == 9)    aux[9]   = 32.0f * scale_en[0] * b3en[0];
        if (tid < D_H)   ws[W3S_OFF + tid] = W3en[tid] * scale_en[0];
        // aT[e][d-1]: pair (e,(e+d)&31) coef 0.25/0.5, d=16 pre-halved (counted twice)
        float* aT = ws + AT_OFF;
#pragma unroll
        for (int q = 0; q < 2; ++q) {
            int idx = tid + q * 256;               // 512 entries
            int e = idx >> 4, dm = idx & 15, d = dm + 1;
            int jn = (e + d) & 31;
            int a = e < jn ? e : jn, b = e < jn ? jn : e;
            float av = mask[a * N_E + b] ? 0.25f : 0.5f;
            if (d == 16) av *= 0.5f;
            aT[e * 16 + dm] = av;
        }
        // W2_en -> bf16 B-fragments: lane l, slot s (m=s>>2, r=s&3):
        //   k = m*16 + (l>>5)*8 + 2r, j = l&31; packed (lo=k, hi=k+1)
        unsigned* wsB = (unsigned*)(ws + B_OFF);
#pragma unroll
        for (int q = 0; q < 2; ++q) {
            int idx = tid + q * 256;               // 512 = 64 lanes x 8 slots
            int lane = idx >> 3, slot = idx & 7;
            int m = slot >> 2, r = slot & 3;
            int k = m * 16 + ((lane >> 5) << 3) + (r << 1);
            int j = lane & 31;
            wsB[lane * 8 + slot] = pk_bf16(W2en[k * D_H + j], W2en[(k + 1) * D_H + j]);
        }
    }
    // ee table: one entry per 32-lane group, lane j = hidden unit
    const int j     = tid & 31;
    const int entry = blockIdx.x * 8 + (tid >> 5);
    const float r   = (float)entry * TAB_H;
    float g = b2ee[j];
#pragma unroll
    for (int k = 0; k < D_H; ++k) g += silu_f(r * W1ee[k] + b1ee[k]) * W2ee[k * D_H + j];
    float o = silu_f(g) * W3ee[j];
#pragma unroll
    for (int m = 16; m; m >>= 1) o += __shfl_xor(o, m, 32);
    if (j == 0) ws[entry] = scale_ee[0] * (o + b3ee[0]);
}

// ---------------- Main kernel: 1 walker per wave, spill-free ----------------
// Lane l: electron e = l&31, k-half kh = l>>5. Layer-1 computed in two
// hidden-unit halves so only 8 float2 are live at a time; each half feeds one
// A fragment in-lane (no cross-lane ops). Work split by kh: e-e d 1-8 / 9-16;
// cusp duplicated with 0.5 weight. No min-waves clause: compiler allocates
// naturally (~50-60 VGPR) -> HW gives 7-8 waves/SIMD without spilling.
__launch_bounds__(256)
__global__ void jastrow_kernel(const float* __restrict__ re, const float* __restrict__ rnuc,
                               const float* __restrict__ charges,
                               const float* __restrict__ W1, const float* __restrict__ b1,
                               const float* __restrict__ b2,
                               const float* __restrict__ ws,
                               float* __restrict__ out)
{
    const int tid = threadIdx.x;
    const int e   = tid & 31;           // electron
    const int kh  = (tid >> 5) & 1;     // k-half / work-split copy
    const int w   = blockIdx.x * WPB + (tid >> 6);
    const float* aux = ws + AUX_OFF;

    const float* cb = re + ((size_t)w * N_E + e) * 3;
    float ex = cb[0], ey = cb[1], ez = cb[2];

    // ---- e-n cusp (duplicated across halves, weighted 0.5) + r^2 ----
    float x[N_NUC];
    float cusp = 0.0f;
#pragma unroll
    for (int n = 0; n < N_NUC; ++n) {
        float dx = ex - rnuc[n * 3 + 0];
        float dy = ey - rnuc[n * 3 + 1];
        float dz = ez - rnuc[n * 3 + 2];
        float r2 = dx * dx + dy * dy + dz * dz;
        x[n] = r2;
        float r = sqrtf(r2);
        cusp -= charges[n] * r * fast_rcp(1.0f + aux[n] * r);
    }
    float acc = 0.5f * cusp;

    // ---- layer 1 + A-fragments, two hidden-unit halves (halves live range) ----
    // half hp covers hidden units [16hp, 16hp+16) = k-range of MFMA hp.
    // Lane keeps k = 16hp + kh*8 + 2r(+1) -> hh[kh*4 + r] of that half.
    FragAB A1, A2;
#pragma unroll
    for (int hp = 0; hp < 2; ++hp) {
        float2 hh[8];
#pragma unroll
        for (int j = 0; j < 8; ++j) hh[j] = ((const float2*)b1)[hp * 8 + j];
#pragma unroll
        for (int k = 0; k < N_NUC; ++k) {
            float xk = x[k];
            const float2* row = (const float2*)(W1 + k * D_H + hp * 16);
#pragma unroll
            for (int j = 0; j < 8; ++j) {
                float2 wv = row[j];
                hh[j].x = fmaf(xk, wv.x, hh[j].x);
                hh[j].y = fmaf(xk, wv.y, hh[j].y);
            }
        }
        FragAB& A = hp ? A2 : A1;       // hp is compile-time (unrolled)
#pragma unroll
        for (int r = 0; r < 4; ++r) {
            float2 s = kh ? hh[4 + r] : hh[r];   // runtime select, static indices
            A.u[r] = pk_bf16(silu_f(s.x), silu_f(s.y));
        }
    }

    // B fragments (wave-shared W2, pre-packed)
    FragAB B1, B2;
    {
        const unsigned* wsB = (const unsigned*)(ws + B_OFF) + (size_t)(tid & 63) * 8;
        uint4 q0 = *(const uint4*)wsB;
        uint4 q1 = *(const uint4*)(wsB + 4);
        B1.u[0] = q0.x; B1.u[1] = q0.y; B1.u[2] = q0.z; B1.u[3] = q0.w;
        B2.u[0] = q1.x; B2.u[1] = q1.y; B2.u[2] = q1.z; B2.u[3] = q1.w;
    }

    float vb2 = b2[e];                              // C init = bias (col j = lane&31)
    f32x16_t accm;
#pragma unroll
    for (int r = 0; r < 16; ++r) accm[r] = vb2;
    accm = __builtin_amdgcn_mfma_f32_32x32x16_bf16(A1.s, B1.s, accm, 0, 0, 0);
    accm = __builtin_amdgcn_mfma_f32_32x32x16_bf16(A2.s, B2.s, accm, 0, 0, 0);

    // epilogue: lane covers 16 of 32 rows for col e; rows across the lane pair
    // are disjoint -> every (row,col) counted once over the wave
    float w3s = ws[W3S_OFF + e];
    float sA = 0.0f;
#pragma unroll
    for (int r = 0; r < 16; ++r) sA += silu_f(accm[r]);
    acc += sA * w3s;

    // ---- e-e: 8 rotation pairs per half (kh=0: d 1..8, kh=1: d 9..16) ----
    float bs = aux[8];
    float av[8];
    {
        const float* aT = ws + AT_OFF + e * 16 + kh * 8;
#pragma unroll
        for (int i = 0; i < 8; ++i) av[i] = aT[i];
    }
#pragma unroll
    for (int dd = 0; dd < 8; ++dd) {
        int d = kh * 8 + dd + 1;
        int jn = (e + d) & 31;
        float cjx = __shfl(ex, jn, 32);
        float cjy = __shfl(ey, jn, 32);
        float cjz = __shfl(ez, jn, 32);
        float dx = ex - cjx, dy = ey - cjy, dz = ez - cjz;
        float r = sqrtf(dx * dx + dy * dy + dz * dz);
        float ct = av[dd] * r * fast_rcp(1.0f + bs * r);
        float t = r * TAB_INVH;
        int i0 = (int)t;
        if (i0 > NTAB - 2) i0 = NTAB - 2;
        float f = t - (float)i0;
        const float* tp = ws + i0;
        float tv = tp[0] + f * (tp[1] - tp[0]);
        if (dd == 7) tv = kh ? 0.5f * tv : tv;      // d=16 pairs counted twice
        acc += ct + tv;
    }

    // ---- reduce 64 lanes (one walker) ----
#pragma unroll
    for (int m = 32; m; m >>= 1) acc += __shfl_xor(acc, m, 64);
    if ((tid & 63) == 0) out[w] = acc + aux[9];
}

extern "C" void kernel_launch(void* const* d_in, const int* in_sizes, int n_in,
                              void* d_out, int out_size, void* d_ws, size_t ws_size,
                              hipStream_t stream)
{
    const float* re       = (const float*)d_in[0];
    const float* rnuc     = (const float*)d_in[1];
    const float* charges  = (const float*)d_in[2];
    const int*   mask     = (const int*)d_in[3];
    const float* b_en     = (const float*)d_in[4];
    const float* b_ee     = (const float*)d_in[5];
    const float* W1_en    = (const float*)d_in[6];
    const float* b1_en    = (const float*)d_in[7];
    const float* W2_en    = (const float*)d_in[8];
    const float* b2_en    = (const float*)d_in[9];
    const float* W3_en    = (const float*)d_in[10];
    const float* b3_en    = (const float*)d_in[11];
    const float* W1_ee    = (const float*)d_in[12];
    const float* b1_ee    = (const float*)d_in[13];
    const float* W2_ee    = (const float*)d_in[14];
    const float* b2_ee    = (const float*)d_in[15];
    const float* W3_ee    = (const float*)d_in[16];
    const float* b3_ee    = (const float*)d_in[17];
    const float* scale_en = (const float*)d_in[18];
    const float* scale_ee = (const float*)d_in[19];

    float* out = (float*)d_out;
    float* ws  = (float*)d_ws;

    build_tables<<<NTAB / 8, 256, 0, stream>>>(W1_ee, b1_ee, W2_ee, b2_ee, W3_ee, b3_ee,
                                               scale_ee, b_en, b_ee, mask,
                                               W2_en, W3_en, b3_en, scale_en, ws);
    jastrow_kernel<<<N_W / WPB, 256, 0, stream>>>(re, rnuc, charges,
                                                  W1_en, b1_en, b2_en, ws, out);
}

// Round 9
// 22.707 us; speedup vs baseline: 3.6701x; 1.8418x over previous
//
#include <hip/hip_runtime.h>

#define N_W   8192
#define N_E   32
#define N_NUC 8
#define D_H   32
#define NTAB  2048
#define TAB_INVH 128.0f    // table step = 1/128, range [0, 16)
#define TAB_H    (1.0f/128.0f)
#define WPB   8            // walkers per block; wave = 2 walkers (lanes 0-31 / 32-63)

// ws layout (float units):
// [0, 8192)      float4 table4[2048]: (cusp_i, dcusp_i, mlp_i, dmlp_i), 32 KB
// [8192, 8208)   aux: [0..7] softplus(b_en), [8] softplus(b_ee), [9] 32*scale_en*b3_en
// [8208, 8224)   masks: 16 u32, bit e of masks[d-1] = spin_parallel(e, (e+d)&31)
// [8224, 8256)   W3*scale_en (32)
// [8256, +512u)  W2 bf16 B-fragments (512 u32)
#define AUX_OFF  8192
#define MSK_OFF  8208
#define W3S_OFF  8224
#define B_OFF    8256

typedef __attribute__((ext_vector_type(8)))  short bf16x8_t;   // 8 bf16 = 4 VGPR
typedef __attribute__((ext_vector_type(16))) float f32x16_t;   // MFMA accumulator

union FragAB { bf16x8_t s; unsigned u[4]; };

__device__ __forceinline__ float fast_rcp(float x) { return __builtin_amdgcn_rcpf(x); }
__device__ __forceinline__ float silu_f(float v)   { return v * fast_rcp(1.0f + __expf(-v)); }
__device__ __forceinline__ unsigned pk_bf16(float lo, float hi) {
    unsigned r;
    asm("v_cvt_pk_bf16_f32 %0, %1, %2" : "=v"(r) : "v"(lo), "v"(hi));
    return r;
}

// ---------------- Pre-kernel: combined float4 table + aux + masks + W2 fragments ----------------
// One table entry per 32-lane group (lane j = hidden unit); each group evaluates the
// ee-MLP at r_i and r_i + h so lane 0 can write (cusp, dcusp, mlp, dmlp) in one float4.
__global__ void build_tables(const float* __restrict__ W1ee, const float* __restrict__ b1ee,
                             const float* __restrict__ W2ee, const float* __restrict__ b2ee,
                             const float* __restrict__ W3ee, const float* __restrict__ b3ee,
                             const float* __restrict__ scale_ee,
                             const float* __restrict__ b_en, const float* __restrict__ b_ee,
                             const int* __restrict__ mask,
                             const float* __restrict__ W2en, const float* __restrict__ W3en,
                             const float* __restrict__ b3en, const float* __restrict__ scale_en,
                             float* __restrict__ ws)
{
    const int tid = threadIdx.x;
    if (blockIdx.x == 0) {
        float* aux = ws + AUX_OFF;
        if (tid < N_NUC) aux[tid] = __logf(1.0f + __expf(b_en[tid]));
        if (tid == 8)    aux[8]   = __logf(1.0f + __expf(b_ee[0]));
        if (tid == 9)    aux[9]   = 32.0f * scale_en[0] * b3en[0];
        if (tid < D_H)   ws[W3S_OFF + tid] = W3en[tid] * scale_en[0];
        if (tid < 16) {   // spin masks, one u32 per rotation distance d = tid+1
            unsigned m = 0;
            int d = tid + 1;
            for (int e = 0; e < N_E; ++e) {
                int jn = (e + d) & 31;
                int a = e < jn ? e : jn, b = e < jn ? jn : e;
                if (mask[a * N_E + b]) m |= (1u << e);
            }
            ((unsigned*)(ws + MSK_OFF))[tid] = m;
        }
        // W2_en -> bf16 B-fragments: lane l, slot s (m=s>>2, r=s&3):
        //   k = m*16 + (l>>5)*8 + 2r, j = l&31; packed (lo=k, hi=k+1)
        unsigned* wsB = (unsigned*)(ws + B_OFF);
#pragma unroll
        for (int q = 0; q < 2; ++q) {
            int idx = tid + q * 256;               // 512 = 64 lanes x 8 slots
            int lane = idx >> 3, slot = idx & 7;
            int m2 = slot >> 2, r = slot & 3;
            int k = m2 * 16 + ((lane >> 5) << 3) + (r << 1);
            int j = lane & 31;
            wsB[lane * 8 + slot] = pk_bf16(W2en[k * D_H + j], W2en[(k + 1) * D_H + j]);
        }
    }
    const int j     = tid & 31;                    // hidden unit (layer 2)
    const int entry = blockIdx.x * 8 + (tid >> 5); // table index
    const float bs  = __logf(1.0f + __expf(b_ee[0]));
    float mlp[2];
#pragma unroll
    for (int t = 0; t < 2; ++t) {
        float r = ((float)entry + (float)t) * TAB_H;
        float g = b2ee[j];
#pragma unroll
        for (int k = 0; k < D_H; ++k) g += silu_f(r * W1ee[k] + b1ee[k]) * W2ee[k * D_H + j];
        float o = silu_f(g) * W3ee[j];
#pragma unroll
        for (int m = 16; m; m >>= 1) o += __shfl_xor(o, m, 32);
        mlp[t] = scale_ee[0] * (o + b3ee[0]);
    }
    if (j == 0) {
        float r0 = (float)entry * TAB_H, r1 = r0 + TAB_H;
        float c0 = r0 * fast_rcp(1.0f + bs * r0);
        float c1 = r1 * fast_rcp(1.0f + bs * r1);
        *(float4*)(ws + 4 * entry) = make_float4(c0, c1 - c0, mlp[0], mlp[1] - mlp[0]);
    }
}

// ---------------- Main kernel (round-6 structure; e-e via one float4 gather/pair) ----------------
// 1 thread = 1 electron; wave = 2 walkers. Layer-2 (32x32) via 2x2 MFMA
// v_mfma_f32_32x32x16_bf16 per wave; W2 pre-packed as B-fragments (2 dwordx4 loads).
// A-fragments: cvt_pk_bf16 + 16 shfl_xor(.,32). e-e pair term: 3 coord shfls +
// sqrt + ONE 16B table gather (cusp AND mlp with deltas) + bitmask spin coef.
__launch_bounds__(256, 4)
__global__ void jastrow_kernel(const float* __restrict__ re, const float* __restrict__ rnuc,
                               const float* __restrict__ charges,
                               const float* __restrict__ W1, const float* __restrict__ b1,
                               const float* __restrict__ b2,
                               const float* __restrict__ ws,
                               float* __restrict__ out)
{
    const int tid  = threadIdx.x;
    const int e    = tid & 31;          // electron
    const int half = (tid >> 5) & 1;    // 0: walker A of wave, 1: walker B
    const int v    = tid >> 5;          // walker slot in block (0..7)
    const int w    = blockIdx.x * WPB + v;
    const float* aux = ws + AUX_OFF;

    const float* cb = re + ((size_t)w * N_E + e) * 3;
    float ex = cb[0], ey = cb[1], ez = cb[2];

    float acc = 0.0f;

    // ---- e-n cusp + r^2 ----
    float x[N_NUC];
#pragma unroll
    for (int n = 0; n < N_NUC; ++n) {
        float dx = ex - rnuc[n * 3 + 0];
        float dy = ey - rnuc[n * 3 + 1];
        float dz = ez - rnuc[n * 3 + 2];
        float r2 = dx * dx + dy * dy + dz * dz;
        x[n] = r2;
        float r = sqrtf(r2);
        acc -= charges[n] * r * fast_rcp(1.0f + aux[n] * r);
    }

    // ---- layer 1: 8 -> 32, fp32 packed, weights via K$ (256 floats) ----
    float2 hh[D_H / 2];
#pragma unroll
    for (int j = 0; j < D_H / 2; ++j) hh[j] = ((const float2*)b1)[j];
#pragma unroll
    for (int k = 0; k < N_NUC; ++k) {
        float xk = x[k];
        const float2* row = (const float2*)(W1 + k * D_H);
#pragma unroll
        for (int j = 0; j < D_H / 2; ++j) {
            float2 wv = row[j];
            hh[j].x = fmaf(xk, wv.x, hh[j].x);
            hh[j].y = fmaf(xk, wv.y, hh[j].y);
        }
    }
    // silu + pack to bf16 pairs: hpk[i] = (h[2i] lo, h[2i+1] hi), k-major
    unsigned hpk[16];
#pragma unroll
    for (int i = 0; i < 16; ++i) hpk[i] = pk_bf16(silu_f(hh[i].x), silu_f(hh[i].y));
    // cross-half exchange: lane l <-> l^32
    unsigned sx[16];
#pragma unroll
    for (int i = 0; i < 16; ++i) sx[i] = (unsigned)__shfl_xor((int)hpk[i], 32, 64);

    // B fragments (wave-shared W2, pre-packed)
    FragAB B1, B2;
    {
        const unsigned* wsB = (const unsigned*)(ws + B_OFF) + (size_t)(tid & 63) * 8;
        uint4 q0 = *(const uint4*)wsB;
        uint4 q1 = *(const uint4*)(wsB + 4);
        B1.u[0] = q0.x; B1.u[1] = q0.y; B1.u[2] = q0.z; B1.u[3] = q0.w;
        B2.u[0] = q1.x; B2.u[1] = q1.y; B2.u[2] = q1.z; B2.u[3] = q1.w;
    }
    // A fragments: lane l supplies row (l&31), k-half (l>>5)*8
    const bool lo = (tid & 32) == 0;
    FragAB A1a, A2a, A1b, A2b;
#pragma unroll
    for (int r = 0; r < 4; ++r) {
        A1a.u[r] = lo ? hpk[r]      : sx[4 + r];    // walker A, k 0..15
        A2a.u[r] = lo ? hpk[8 + r]  : sx[12 + r];   // walker A, k 16..31
        A1b.u[r] = lo ? sx[r]       : hpk[4 + r];   // walker B, k 0..15
        A2b.u[r] = lo ? sx[8 + r]   : hpk[12 + r];  // walker B, k 16..31
    }
    float vb2 = b2[e];                              // C init = bias (col j = lane&31)
    f32x16_t accA, accB;
#pragma unroll
    for (int r = 0; r < 16; ++r) { accA[r] = vb2; accB[r] = vb2; }
    accA = __builtin_amdgcn_mfma_f32_32x32x16_bf16(A1a.s, B1.s, accA, 0, 0, 0);
    accA = __builtin_amdgcn_mfma_f32_32x32x16_bf16(A2a.s, B2.s, accA, 0, 0, 0);
    accB = __builtin_amdgcn_mfma_f32_32x32x16_bf16(A1b.s, B1.s, accB, 0, 0, 0);
    accB = __builtin_amdgcn_mfma_f32_32x32x16_bf16(A2b.s, B2.s, accB, 0, 0, 0);

    // epilogue: sum silu over rows (electrons), weight by W3*scale (col j = lane&31)
    float w3s = ws[W3S_OFF + e];
    float sA = 0.0f, sB = 0.0f;
#pragma unroll
    for (int r = 0; r < 16; ++r) { sA += silu_f(accA[r]); sB += silu_f(accB[r]); }
    float mlpA = sA * w3s, mlpB = sB * w3s;

    // ---- e-e: rotation pairs; spin coef from SGPR bitmask, one float4 gather/pair ----
    unsigned mks[16];
    {
        const unsigned* mp = (const unsigned*)(ws + MSK_OFF);
#pragma unroll
        for (int i = 0; i < 16; ++i) mks[i] = mp[i];
    }
#pragma unroll
    for (int d = 1; d <= 16; ++d) {
        int jn = (e + d) & 31;
        float cjx = __shfl(ex, jn, 32);
        float cjy = __shfl(ey, jn, 32);
        float cjz = __shfl(ez, jn, 32);
        float dx = ex - cjx, dy = ey - cjy, dz = ez - cjz;
        float r = sqrtf(dx * dx + dy * dy + dz * dz);
        float t = r * TAB_INVH;
        int i0 = (int)t;
        if (i0 > NTAB - 2) i0 = NTAB - 2;
        float f = t - (float)i0;
        float4 T = *(const float4*)(ws + 4 * i0);   // (cusp, dcusp, mlp, dmlp)
        float a = ((mks[d - 1] >> e) & 1u) ? 0.25f : 0.5f;
        float pv = a * fmaf(f, T.y, T.x) + fmaf(f, T.w, T.z);
        acc += (d == 16) ? 0.5f * pv : pv;          // d=16 pairs counted twice
    }

    // ---- per-walker totals: MLP part spans all 64 lanes, ee/cusp per 32-half ----
    float valA = mlpA + (half ? 0.0f : acc);
    float valB = mlpB + (half ? acc : 0.0f);
#pragma unroll
    for (int m = 32; m; m >>= 1) {
        valA += __shfl_xor(valA, m, 64);
        valB += __shfl_xor(valB, m, 64);
    }
    if ((tid & 63) == 0) {
        int wA = blockIdx.x * WPB + ((tid >> 6) << 1);
        out[wA]     = valA + aux[9];
        out[wA + 1] = valB + aux[9];
    }
}

extern "C" void kernel_launch(void* const* d_in, const int* in_sizes, int n_in,
                              void* d_out, int out_size, void* d_ws, size_t ws_size,
                              hipStream_t stream)
{
    const float* re       = (const float*)d_in[0];
    const float* rnuc     = (const float*)d_in[1];
    const float* charges  = (const float*)d_in[2];
    const int*   mask     = (const int*)d_in[3];
    const float* b_en     = (const float*)d_in[4];
    const float* b_ee     = (const float*)d_in[5];
    const float* W1_en    = (const float*)d_in[6];
    const float* b1_en    = (const float*)d_in[7];
    const float* W2_en    = (const float*)d_in[8];
    const float* b2_en    = (const float*)d_in[9];
    const float* W3_en    = (const float*)d_in[10];
    const float* b3_en    = (const float*)d_in[11];
    const float* W1_ee    = (const float*)d_in[12];
    const float* b1_ee    = (const float*)d_in[13];
    const float* W2_ee    = (const float*)d_in[14];
    const float* b2_ee    = (const float*)d_in[15];
    const float* W3_ee    = (const float*)d_in[16];
    const float* b3_ee    = (const float*)d_in[17];
    const float* scale_en = (const float*)d_in[18];
    const float* scale_ee = (const float*)d_in[19];

    float* out = (float*)d_out;
    float* ws  = (float*)d_ws;

    build_tables<<<NTAB / 8, 256, 0, stream>>>(W1_ee, b1_ee, W2_ee, b2_ee, W3_ee, b3_ee,
                                               scale_ee, b_en, b_ee, mask,
                                               W2_en, W3_en, b3_en, scale_en, ws);
    jastrow_kernel<<<N_W / WPB, 256, 0, stream>>>(re, rnuc, charges,
                                                  W1_en, b1_en, b2_en, ws, out);
}

// Round 10
// 21.228 us; speedup vs baseline: 3.9258x; 1.0697x over previous
//
#include <hip/hip_runtime.h>

#define N_W   8192
#define N_E   32
#define N_NUC 8
#define D_H   32
#define NTAB  2048
#define TAB_INVH 128.0f    // table step = 1/128, range [0, 16)
#define TAB_H    (1.0f/128.0f)
#define WPB   8            // walkers per block; wave = 2 walkers (lanes 0-31 / 32-63)

// ws layout (float units):
// [0, 4096)      float2 nodes[2048]: (cusp_i, mlp_i)        16 KB
// [4096, 4112)   aux: [0..7] sp(b_en), [8] sp(b_ee), [9] 32*scale_en*b3_en
// [4112, 4128)   masks: 16 u32, bit e of masks[d-1] = spin_parallel(e,(e+d)&31)
// [4128, 4160)   W3*scale_en [32]
// [4160, 4416)   W1T bf16 A-fragments (256 u32): rows=hidden j, k=nuc 0..7, k8=b1
// [4416, 4928)   W2T bf16 A-fragments (512 u32): rows=out j', k=hidden 0..31
#define AUX_OFF 4096
#define MSK_OFF 4112
#define W3S_OFF 4128
#define W1T_OFF 4160
#define W2T_OFF 4416

typedef __attribute__((ext_vector_type(8)))  short bf16x8_t;   // 8 bf16 = 4 VGPR
typedef __attribute__((ext_vector_type(16))) float f32x16_t;   // MFMA accumulator

union FragAB { bf16x8_t s; unsigned u[4]; };

__device__ __forceinline__ float fast_rcp(float x) { return __builtin_amdgcn_rcpf(x); }
__device__ __forceinline__ float silu_f(float v)   { return v * fast_rcp(1.0f + __expf(-v)); }
__device__ __forceinline__ unsigned pk_bf16(float lo, float hi) {
    unsigned r;
    asm("v_cvt_pk_bf16_f32 %0, %1, %2" : "=v"(r) : "v"(lo), "v"(hi));
    return r;
}

// ---------------- Pre-kernel: float2 node table + aux + masks + W1T/W2T fragments --------
// 512 blocks x 256. One table entry per 64-lane group: lane j = hidden unit, k-half
// (tid>>5)&1 covers 16 of the 32 layer-2 k terms; one shfl_xor(32) combines.
__global__ void build_tables(const float* __restrict__ W1ee, const float* __restrict__ b1ee,
                             const float* __restrict__ W2ee, const float* __restrict__ b2ee,
                             const float* __restrict__ W3ee, const float* __restrict__ b3ee,
                             const float* __restrict__ scale_ee,
                             const float* __restrict__ b_en, const float* __restrict__ b_ee,
                             const int* __restrict__ mask,
                             const float* __restrict__ W1en, const float* __restrict__ b1en,
                             const float* __restrict__ W2en, const float* __restrict__ W3en,
                             const float* __restrict__ b3en, const float* __restrict__ scale_en,
                             float* __restrict__ ws)
{
    const int tid = threadIdx.x;
    if (blockIdx.x == 0) {
        float* aux = ws + AUX_OFF;
        if (tid < N_NUC) aux[tid] = __logf(1.0f + __expf(b_en[tid]));
        if (tid == 8)    aux[8]   = __logf(1.0f + __expf(b_ee[0]));
        if (tid == 9)    aux[9]   = 32.0f * scale_en[0] * b3en[0];
        if (tid >= 32 && tid < 64) ws[W3S_OFF + tid - 32] = W3en[tid - 32] * scale_en[0];
        if (tid >= 64 && tid < 80) {       // spin masks, d = tid-63
            int d = tid - 63;
            unsigned m = 0;
            for (int e2 = 0; e2 < N_E; ++e2) {
                int jn = (e2 + d) & 31;
                int a = e2 < jn ? e2 : jn, b = e2 < jn ? jn : e2;
                if (mask[a * N_E + b]) m |= (1u << e2);
            }
            ((unsigned*)(ws + MSK_OFF))[d - 1] = m;
        }
        {   // W1T A-fragments: lane L row j=L&31; lo lanes k0..7 = W1[k][j]; hi: k8=b1[j]
            int L = tid >> 2, r = tid & 3, j = L & 31;
            unsigned u = 0;
            if (L < 32)      u = pk_bf16(W1en[(2 * r) * D_H + j], W1en[(2 * r + 1) * D_H + j]);
            else if (r == 0) u = pk_bf16(b1en[j], 0.0f);
            ((unsigned*)(ws + W1T_OFF))[(L << 2) + r] = u;
        }
#pragma unroll
        for (int q = 0; q < 2; ++q) {      // W2T A-fragments (512 u32)
            int idx = tid + (q << 8);
            int L = idx >> 3, s = idx & 7, j = L & 31;
            int kb = ((L >> 5) << 3) + ((s & 3) << 1) + ((s >> 2) << 4);
            ((unsigned*)(ws + W2T_OFF))[(L << 3) + s] =
                pk_bf16(W2en[kb * D_H + j], W2en[(kb + 1) * D_H + j]);
        }
    }
    // ---- ee table node ----
    const int entry = blockIdx.x * 4 + (tid >> 6);
    const int j = tid & 31, kh = (tid >> 5) & 1;
    const float r = (float)entry * TAB_H;
    float g = kh ? 0.0f : b2ee[j];
#pragma unroll
    for (int kk = 0; kk < 16; ++kk) {
        int k = kh * 16 + kk;
        g += silu_f(r * W1ee[k] + b1ee[k]) * W2ee[k * D_H + j];
    }
    g += __shfl_xor(g, 32, 64);
    float o = silu_f(g) * W3ee[j];
#pragma unroll
    for (int m = 16; m; m >>= 1) o += __shfl_xor(o, m, 32);
    if ((tid & 63) == 0) {
        float bs = __logf(1.0f + __expf(b_ee[0]));
        float c = r * fast_rcp(1.0f + bs * r);
        *(float2*)(ws + 2 * entry) = make_float2(c, scale_ee[0] * (o + b3ee[0]));
    }
}

// ---------------- Main kernel: full-MFMA MLP, no weight s_load streams ----------------
// Wave = 2 walkers. Layer 1: H^T = W1T(A, prepacked; b1 via one-hot k=8) @ x^T(B, in-lane
// bf16-packed x, walker-B x via 4 shfl_xor). D1: col=electron(lane&31), rows=hidden
// (row = (r&3)+8(r>>2)+4(lane>>5)). Layer 2: G^T = W2T(A, prepacked) @ silu(H^T)(B, built
// by 8 pk + 8 shfl_xor + selects per walker). Epilogue per lane: sum silu(G)*W3s over its
// 16 rows. e-e: shfl partners + 2 float2 node gathers + bitmask spin coefs.
__launch_bounds__(256, 4)
__global__ void jastrow_kernel(const float* __restrict__ re, const float* __restrict__ rnuc,
                               const float* __restrict__ charges,
                               const float* __restrict__ b2,
                               const float* __restrict__ ws,
                               float* __restrict__ out)
{
    const int tid  = threadIdx.x;
    const int e    = tid & 31;          // electron
    const int lane = tid & 63;
    const bool lo  = (tid & 32) == 0;
    const int w    = blockIdx.x * WPB + (tid >> 5);
    const float* aux = ws + AUX_OFF;

    const float* cb = re + ((size_t)w * N_E + e) * 3;
    float ex = cb[0], ey = cb[1], ez = cb[2];

    float acc = 0.0f;

    // ---- e-n cusp + r^2 ----
    float x[N_NUC];
#pragma unroll
    for (int n = 0; n < N_NUC; ++n) {
        float dx = ex - rnuc[n * 3 + 0];
        float dy = ey - rnuc[n * 3 + 1];
        float dz = ez - rnuc[n * 3 + 2];
        float r2 = dx * dx + dy * dy + dz * dz;
        x[n] = r2;
        float r = sqrtf(r2);
        acc -= charges[n] * r * fast_rcp(1.0f + aux[n] * r);
    }

    // ---- pack x to bf16; exchange across halves for walker-B's MFMA ----
    unsigned xpk[4], sxp[4];
#pragma unroll
    for (int r = 0; r < 4; ++r) xpk[r] = pk_bf16(x[2 * r], x[2 * r + 1]);
#pragma unroll
    for (int r = 0; r < 4; ++r) sxp[r] = (unsigned)__shfl_xor((int)xpk[r], 32, 64);

    // B operands for layer-1 MFMAs: lo lanes k0..7 = x pairs; hi lanes k8 = 1.0 (b1 hook)
    FragAB B1A, B1B;
#pragma unroll
    for (int r = 0; r < 4; ++r) {
        unsigned oneh = (r == 0) ? 0x00003F80u : 0u;   // bf16 (1.0, 0.0)
        B1A.u[r] = lo ? xpk[r] : oneh;
        B1B.u[r] = lo ? sxp[r] : oneh;
    }
    FragAB A1;
    {
        uint4 q = *((const uint4*)((const unsigned*)(ws + W1T_OFF) + (lane << 2)));
        A1.u[0] = q.x; A1.u[1] = q.y; A1.u[2] = q.z; A1.u[3] = q.w;
    }
    f32x16_t z;
#pragma unroll
    for (int r = 0; r < 16; ++r) z[r] = 0.0f;
    f32x16_t HA = __builtin_amdgcn_mfma_f32_32x32x16_bf16(A1.s, B1A.s, z, 0, 0, 0);
    f32x16_t HB = __builtin_amdgcn_mfma_f32_32x32x16_bf16(A1.s, B1B.s, z, 0, 0, 0);

    // layer-2 A operands (prepacked W2T) + row-indexed b2 / W3s values
    FragAB A2a, A2b;
    {
        const unsigned* p = (const unsigned*)(ws + W2T_OFF) + ((size_t)lane << 3);
        uint4 q0 = *(const uint4*)p;
        uint4 q1 = *(const uint4*)(p + 4);
        A2a.u[0] = q0.x; A2a.u[1] = q0.y; A2a.u[2] = q0.z; A2a.u[3] = q0.w;
        A2b.u[0] = q1.x; A2b.u[1] = q1.y; A2b.u[2] = q1.z; A2b.u[3] = q1.w;
    }
    float b2v[16], w3v[16];
    {
        const float* b2q = b2 + ((lane >> 5) << 2);
        const float* w3q = ws + W3S_OFF + ((lane >> 5) << 2);
#pragma unroll
        for (int r = 0; r < 16; ++r) {
            int ri = (r & 3) + ((r >> 2) << 3);
            b2v[r] = b2q[ri];
            w3v[r] = w3q[ri];
        }
    }

    float sA, sB;
#pragma unroll
    for (int wk = 0; wk < 2; ++wk) {                   // walker A then B
        const f32x16_t& H = wk ? HB : HA;
        unsigned p[8], sx2[8];
#pragma unroll
        for (int i = 0; i < 8; ++i)
            p[i] = pk_bf16(silu_f(H[2 * i]), silu_f(H[2 * i + 1]));
#pragma unroll
        for (int i = 0; i < 8; ++i) sx2[i] = (unsigned)__shfl_xor((int)p[i], 32, 64);
        FragAB Ba, Bb;
        Ba.u[0] = lo ? p[0]   : sx2[2];
        Ba.u[1] = lo ? p[1]   : sx2[3];
        Ba.u[2] = lo ? sx2[0] : p[2];
        Ba.u[3] = lo ? sx2[1] : p[3];
        Bb.u[0] = lo ? p[4]   : sx2[6];
        Bb.u[1] = lo ? p[5]   : sx2[7];
        Bb.u[2] = lo ? sx2[4] : p[6];
        Bb.u[3] = lo ? sx2[5] : p[7];
        f32x16_t g;
#pragma unroll
        for (int r = 0; r < 16; ++r) g[r] = b2v[r];
        g = __builtin_amdgcn_mfma_f32_32x32x16_bf16(A2a.s, Ba.s, g, 0, 0, 0);
        g = __builtin_amdgcn_mfma_f32_32x32x16_bf16(A2b.s, Bb.s, g, 0, 0, 0);
        float s = 0.0f;
#pragma unroll
        for (int r = 0; r < 16; ++r) s += silu_f(g[r]) * w3v[r];
        if (wk == 0) sA = s; else sB = s;
    }

    // ---- e-e: rotation pairs; spin coef from SGPR bitmask, 2 float2 node gathers ----
    unsigned mks[16];
    {
        const unsigned* mp = (const unsigned*)(ws + MSK_OFF);
#pragma unroll
        for (int i = 0; i < 16; ++i) mks[i] = mp[i];
    }
    float bs = aux[8];
#pragma unroll
    for (int d = 1; d <= 16; ++d) {
        int jn = (e + d) & 31;
        float cjx = __shfl(ex, jn, 32);
        float cjy = __shfl(ey, jn, 32);
        float cjz = __shfl(ez, jn, 32);
        float dx = ex - cjx, dy = ey - cjy, dz = ez - cjz;
        float r = sqrtf(dx * dx + dy * dy + dz * dz);
        float t = r * TAB_INVH;
        int i0 = (int)t;
        if (i0 > NTAB - 2) i0 = NTAB - 2;
        float f = t - (float)i0;
        const float* np = ws + (i0 << 1);
        float c0 = np[0], m0 = np[1], c1 = np[2], m1 = np[3];
        float a = ((mks[d - 1] >> e) & 1u) ? 0.25f : 0.5f;
        float pv = a * fmaf(f, c1 - c0, c0) + fmaf(f, m1 - m0, m0);
        acc += (d == 16) ? 0.5f * pv : pv;             // d=16 pairs counted twice
    }

    // ---- per-walker totals; 64-lane reduce; write 2 walkers ----
    float valA = sA + (lo ? acc : 0.0f);
    float valB = sB + (lo ? 0.0f : acc);
#pragma unroll
    for (int m = 32; m; m >>= 1) {
        valA += __shfl_xor(valA, m, 64);
        valB += __shfl_xor(valB, m, 64);
    }
    if ((tid & 63) == 0) {
        int wA = blockIdx.x * WPB + ((tid >> 6) << 1);
        out[wA]     = valA + aux[9];
        out[wA + 1] = valB + aux[9];
    }
}

extern "C" void kernel_launch(void* const* d_in, const int* in_sizes, int n_in,
                              void* d_out, int out_size, void* d_ws, size_t ws_size,
                              hipStream_t stream)
{
    const float* re       = (const float*)d_in[0];
    const float* rnuc     = (const float*)d_in[1];
    const float* charges  = (const float*)d_in[2];
    const int*   mask     = (const int*)d_in[3];
    const float* b_en     = (const float*)d_in[4];
    const float* b_ee     = (const float*)d_in[5];
    const float* W1_en    = (const float*)d_in[6];
    const float* b1_en    = (const float*)d_in[7];
    const float* W2_en    = (const float*)d_in[8];
    const float* b2_en    = (const float*)d_in[9];
    const float* W3_en    = (const float*)d_in[10];
    const float* b3_en    = (const float*)d_in[11];
    const float* W1_ee    = (const float*)d_in[12];
    const float* b1_ee    = (const float*)d_in[13];
    const float* W2_ee    = (const float*)d_in[14];
    const float* b2_ee    = (const float*)d_in[15];
    const float* W3_ee    = (const float*)d_in[16];
    const float* b3_ee    = (const float*)d_in[17];
    const float* scale_en = (const float*)d_in[18];
    const float* scale_ee = (const float*)d_in[19];

    float* out = (float*)d_out;
    float* ws  = (float*)d_ws;

    build_tables<<<NTAB / 4, 256, 0, stream>>>(W1_ee, b1_ee, W2_ee, b2_ee, W3_ee, b3_ee,
                                               scale_ee, b_en, b_ee, mask,
                                               W1_en, b1_en, W2_en, W3_en, b3_en, scale_en,
                                               ws);
    jastrow_kernel<<<N_W / WPB, 256, 0, stream>>>(re, rnuc, charges, b2_en, ws, out);
}